// Round 10
// baseline (554.818 us; speedup 1.0000x reference)
//
#include <hip/hip_runtime.h>
#include <hip/hip_bf16.h>
#include <stdint.h>

// ---- problem constants ----
#define NB   65536      // batch points
#define NC   2
#define NV   3
#define ND   64
#define NK   1024       // codebook entries
#define NS   4
#define NH   1024
#define NL   5
#define NF   25
#define NIN  102
#define K0P  128        // padded layer-0 K

typedef float f32x4  __attribute__((ext_vector_type(4)));
typedef float f32x16 __attribute__((ext_vector_type(16)));
typedef int   i32x4  __attribute__((ext_vector_type(4)));
typedef int   i32x8  __attribute__((ext_vector_type(8)));
typedef unsigned char u8;

__device__ __forceinline__ void load_lds16(const void* g, void* l) {
    __builtin_amdgcn_global_load_lds(
        (const __attribute__((address_space(1))) void*)g,
        (__attribute__((address_space(3))) void*)l,
        16, 0, 0);
}

// fp8 e4m3 scalar convert (RNE, saturating): low byte of cvt_pk
__device__ __forceinline__ u8 to_fp8(float x) {
    return (u8)(__builtin_amdgcn_cvt_pk_fp8_f32(x, 0.0f, 0, false) & 0xff);
}

// 32x32x64 MX-fp8 MFMA. Swapped operands: src0 = W (n-dim on D "rows"),
// src1 = A (m-dim on D "cols"). D: col = lane&31 (m), row(n) =
// (reg&3) + 8*(reg>>2) + 4*(lane>>5), reg in [0,16).
__device__ __forceinline__ f32x16 mfma32(i32x8 wf, i32x8 af, f32x16 c) {
    return __builtin_amdgcn_mfma_scale_f32_32x32x64_f8f6f4(
        wf, af, c, 0, 0,
        0, 0x79797979,    // scale src0 (W): 2^-6
        0, 0x7f7f7f7f);   // scale src1 (A): 2^0
}

// ===========================================================================
// TILED OPERAND LAYOUTS (R21 — 32x32x64 fragments, half-split for stride-16)
// Fragment need (both operands): lane l holds X[row = 32-tile + (l&31)]
//   [k = ks*64 + (l>>5)*32 + 0..31], i.e. kh = l>>5, r32 = l&31, 32 k-bytes.
// Half-split storage of each (tile, ks) 2 KB chunk: [h(2)][kh(2)][r32(32)]
//   [b16(16)], h = upper/lower 16 of the 32 k-bytes. Then lane l reads
//   lo = chunk + l*16, hi = chunk + 1024 + l*16 (both stride-16: conflict-
//   free ds_read_b128 / fully-coalesced global dwordx4).
//  W_t: per bn (128 n): [ks(K/64)][j32(4)][h][kh][r32][b16]
//       -> per-(bn, 128-K iter) slab = 16 KB contiguous (2 ks) for staging.
//  A_t: [m32][ks(K/64)][h][kh][r32][b16] -> 2 KB chunk per (m32, ks).
// ===========================================================================

// ---------------------------------------------------------------------------
// VQ kernel: single block, 1024 threads (one codebook row per thread). fp32.
// R22: ssq sum wave-parallelized (was a 64-iter serial loop on t==0, x4).
// ---------------------------------------------------------------------------
__global__ __launch_bounds__(1024) void vq_kernel(
    const float* __restrict__ latents, const int* __restrict__ latent_idx,
    const float* __restrict__ codebooks, float* __restrict__ zq_out,
    float* __restrict__ out) {
    __shared__ float zcur[ND], resid[ND], zqsum[ND], ssq[ND];
    __shared__ float sDw[16];
    __shared__ int   sKw[16];
    __shared__ int   sBest;
    int t = threadIdx.x, lane = t & 63, wv = t >> 6;
    const float* img = latents + (size_t)latent_idx[0] * (NS * ND);
    if (t < ND) { resid[t] = 0.f; zqsum[t] = 0.f; }
    __syncthreads();
    float lossAcc = 0.f;   // thread 0 only
    for (int s = 0; s < NS; s++) {
        if (t < ND) {
            float iv = img[s * ND + t];
            float r  = resid[t] + iv;
            resid[t] = r;
            zcur[t]  = (s == 0) ? iv : (r - zqsum[t]);
        }
        __syncthreads();
        float zz = 0.f;
#pragma unroll
        for (int d = 0; d < ND; d++) { float z = zcur[d]; zz += z * z; }
        const float4* e4 = (const float4*)(codebooks + ((size_t)s * NK + t) * ND);
        float dot = 0.f, ee = 0.f;
#pragma unroll
        for (int i = 0; i < 16; i++) {
            float4 v = e4[i];
            dot += zcur[4 * i + 0] * v.x; dot += zcur[4 * i + 1] * v.y;
            dot += zcur[4 * i + 2] * v.z; dot += zcur[4 * i + 3] * v.w;
            ee  += v.x * v.x; ee += v.y * v.y; ee += v.z * v.z; ee += v.w * v.w;
        }
        float dmin = zz - 2.0f * dot + ee;
        int   kmin = t;
#pragma unroll
        for (int m = 1; m < 64; m <<= 1) {
            float d2 = __shfl_xor(dmin, m);
            int   k2 = __shfl_xor(kmin, m);
            if (d2 < dmin || (d2 == dmin && k2 < kmin)) { dmin = d2; kmin = k2; }
        }
        if (lane == 0) { sDw[wv] = dmin; sKw[wv] = kmin; }
        __syncthreads();
        if (t == 0) {
            float bd = sDw[0]; int bk = sKw[0];
            for (int w = 1; w < 16; w++) {
                float d2 = sDw[w]; int k2 = sKw[w];
                if (d2 < bd || (d2 == bd && k2 < bk)) { bd = d2; bk = k2; }
            }
            sBest = bk;
            out[NB * NV + s] = (float)bk;
        }
        __syncthreads();
        int best = sBest;
        const float* eb = codebooks + ((size_t)s * NK + best) * ND;
        if (t < ND) {
            float zq = eb[t];
            float d  = zq - zcur[t];
            ssq[t]   = d * d;
            zqsum[t] = zqsum[t] + (zq + (zcur[t] - zq));   // z_q_st forward (exact ref arith)
        }
        __syncthreads();
        if (t < 64) {   // wave 0: parallel 64-wide sum (was serial on t==0)
            float sum = ssq[t];
#pragma unroll
            for (int m = 1; m < 64; m <<= 1) sum += __shfl_xor(sum, m);
            if (t == 0) lossAcc += 0.25f * (sum / (float)ND);
        }
    }
    if (t < ND) zq_out[t] = zqsum[t];
    if (t == 0) out[NB * NV + NS] = lossAcc;
}

// ---------------------------------------------------------------------------
// betas (fused with decoder biases) + out-init, one launch (R22).
// g < 5120: betas; else: out[g-5120] = bout[(g-5120) % NV].
// ---------------------------------------------------------------------------
__global__ __launch_bounds__(256) void betas_init_kernel(
    const float* __restrict__ zq, const float* __restrict__ mod_W,
    const float* __restrict__ mod_b, const float* __restrict__ b0,
    const float* __restrict__ bh, float* __restrict__ bb,
    const float* __restrict__ bout, float* __restrict__ out) {
    int g = blockIdx.x * 256 + threadIdx.x;
    if (g < 5120) {
        int l = g >> 10, n = g & 1023;
        float acc = mod_b[g];
        for (int d = 0; d < ND; d++) acc += zq[d] * mod_W[(size_t)(l * ND + d) * NH + n];
        acc += (l == 0) ? b0[n] : bh[(size_t)(l - 1) * NH + n];
        bb[g] = acc;
    } else {
        int o = g - 5120;
        if (o < NB * NV) out[o] = bout[o % NV];
    }
}

// ---------------------------------------------------------------------------
// Weight prep (R22: both W0 and Wh in ONE launch, z-keyed):
// fp32 [Ks][1024] -> fp8 e4m3 W_t (32x32x64 half-split tiling, x64 scale
// undone by the MFMA e8m0 scale 2^-6). Zero-pad k>=Ks.
// z<4: Wh layer z (Ks=Kp=NH). z==4: W0 (Ks=NIN, Kp=K0P; only x<4 active).
// ---------------------------------------------------------------------------
__global__ __launch_bounds__(256) void prep_kernel(
    const float* __restrict__ dec_W0, const float* __restrict__ dec_Wh,
    u8* __restrict__ W0T, u8* __restrict__ WhT) {
    int z = blockIdx.z;
    const float* src; u8* dst; int Ks, Kp;
    if (z < 4) {
        src = dec_Wh + (size_t)z * NH * NH; dst = WhT + (size_t)z * NH * NH;
        Ks = NH; Kp = NH;
    } else {
        if (blockIdx.x >= 4) return;   // whole block returns: barrier-safe
        src = dec_W0; dst = W0T; Ks = NIN; Kp = K0P;
    }
    __shared__ float tile[32][33];
    int k0 = blockIdx.x * 32, n0 = blockIdx.y * 32;
    int tx = threadIdx.x, ty = threadIdx.y;   // (32, 8)
    for (int i = 0; i < 4; i++) {
        int k = k0 + ty + i * 8;
        int n = n0 + tx;
        tile[ty + i * 8][tx] = (k < Ks) ? src[(size_t)k * NH + n] : 0.0f;
    }
    __syncthreads();
    for (int i = 0; i < 4; i++) {
        int n = n0 + ty + i * 8;
        int k = k0 + tx;
        int bn = n >> 7, j32 = (n >> 5) & 3, r32 = n & 31;
        int ks = k >> 6, kh = (k >> 5) & 1, h = (k >> 4) & 1, b16 = k & 15;
        size_t flat = (size_t)bn * ((size_t)Kp * 128)
                    + ((size_t)(((ks * 4 + j32) * 2 + h) * 2 + kh) * 32 + r32) * 16 + b16;
        dst[flat] = to_fp8(tile[tx][ty + i * 8] * 64.0f);
    }
}

// ---------------------------------------------------------------------------
// Positional encoding value (used in-register by the fused layer-0 GEMM)
// ---------------------------------------------------------------------------
__device__ __forceinline__ float pe_val2(float cx, float cy, int k) {
    if (k < 2) return (k == 0) ? cx : cy;
    if (k >= NIN) return 0.0f;
    int u = k - 2;
    int f = u >> 2, r = u & 3;
    float c = (r & 1) ? cy : cx;
    float a = c * __builtin_ldexpf(3.14159274101257324f, f);
    return (r < 2) ? sinf(a) : cosf(a);
}

// ---------------------------------------------------------------------------
// MX-fp8 MFMA GEMM, R22: R21's verified 32x32x64 skeleton.
//  - NH path unchanged except ONE memory-clobber fence pinning the it+1
//    prefetch issues (gload_lds + A dwordx4) before the MFMA block's
//    ds_reads (order-only; no liveness change; VGPR 116 -> expect same).
//  - K0P path now FUSES the positional encoding: A-fragments are computed
//    in-register via pe_val2 (mapping verified against the former
//    pe_kernel <-> LDPAIR pair: lane reads k = ks*64 + hl*32 + e*4 + j).
//    Removes the pe kernel launch + 8 MB write + 8 MB read.
// Structure: 256m x 128n block, 4 waves of 64m x 128n (2 m-tiles x 4
// n-tiles of 32), 256 thr, launch_bounds(256,2), W via 2 x 16 KB LDS dbuf
// staged per 128-K iter, A direct global->reg, ONE __syncthreads per iter.
// MODE 0: relu(acc+bb) -> fp8, repack to next layer's A_t via LDS, coalesced.
// MODE 1: out[m][v] += relu(acc+bb).Wout[n][v], lane^32 shfl + atomicAdd.
// ---------------------------------------------------------------------------
template <int MODE, int KT>
__global__ __launch_bounds__(256, 2) void gemm_kernel(
    const u8* __restrict__ A, const u8* __restrict__ W,
    const float* __restrict__ bb, u8* __restrict__ O,
    const float* __restrict__ Wout, float* __restrict__ out,
    const float* __restrict__ coords, int Mb) {
    __shared__ __align__(16) u8 smem[32768];
    int t   = threadIdx.x;
    int fid = blockIdx.x;
    int xcd = fid & 7;
    int j8  = fid >> 3;                 // 0..Mb-1
    int bn  = j8 & 7;                   // fastest within an XCD
    int bm  = xcd * (Mb >> 3) + (j8 >> 3);
    int lane = t & 63, wm = t >> 6;     // wave owns m-slice wm*64..+63
    int r32  = lane & 31, hl = lane >> 5;
    constexpr int nIt = KT >> 7;        // 128-K iters
    constexpr int nKs = KT >> 6;        // 64-K steps

    const u8* wslab = W + (size_t)bn * ((size_t)KT * 128);
    const u8* abase = A + ((size_t)(bm * 8 + wm * 2) * nKs) * 2048 + lane * 16;

    f32x16 acc[2][4];
#pragma unroll
    for (int i = 0; i < 2; i++)
#pragma unroll
        for (int j = 0; j < 4; j++)
#pragma unroll
            for (int e = 0; e < 16; e++) acc[i][j][e] = 0.0f;

    // A frags for k-step KS (global): dst[mt], 8 VGPR each
#define LOAD_AF(dst, KS)                                                       \
    {                                                                          \
        _Pragma("unroll")                                                      \
        for (int mt = 0; mt < 2; mt++) {                                       \
            const u8* p = abase + ((size_t)mt * nKs + (KS)) * 2048;            \
            i32x4 lo = *(const i32x4*)(p);                                     \
            i32x4 hi = *(const i32x4*)(p + 1024);                              \
            dst[mt] = __builtin_shufflevector(lo, hi, 0, 1, 2, 3, 4, 5, 6, 7); \
        }                                                                      \
    }
    // one 64-K half of an iter: 4 W-frag reads + 8 MFMA
#define MFMA_HALF(base, KSL, AF)                                               \
    {                                                                          \
        _Pragma("unroll")                                                      \
        for (int j = 0; j < 4; j++) {                                          \
            const u8* c = (base) + (KSL) * 8192 + j * 2048 + lane * 16;        \
            i32x4 lo = *(const i32x4*)(c);                                     \
            i32x4 hi = *(const i32x4*)(c + 1024);                              \
            i32x8 wf = __builtin_shufflevector(lo, hi, 0, 1, 2, 3, 4, 5, 6, 7);\
            acc[0][j] = mfma32(wf, AF[0], acc[0][j]);                          \
            acc[1][j] = mfma32(wf, AF[1], acc[1][j]);                          \
        }                                                                      \
    }

    if constexpr (nIt == 1) {
        // ---- K0P path: single 16 KB slab; PE computed in-register ----
#pragma unroll
        for (int p = 0; p < 4; p++) {
            int g = p * 256 + t;
            load_lds16((const void*)(wslab + g * 16), (void*)(smem + g * 16));
        }
        i32x8 af0[2], af1[2];
#pragma unroll
        for (int mt = 0; mt < 2; mt++) {
            int m = bm * 256 + wm * 64 + mt * 32 + r32;
            float cx = coords[m * 2 + 0], cy = coords[m * 2 + 1];
#pragma unroll
            for (int ks = 0; ks < 2; ks++) {
                i32x8 v;
#pragma unroll
                for (int e = 0; e < 8; e++) {
                    int kb = ks * 64 + hl * 32 + e * 4;
                    int p = __builtin_amdgcn_cvt_pk_fp8_f32(
                        pe_val2(cx, cy, kb + 0), pe_val2(cx, cy, kb + 1), 0, false);
                    p = __builtin_amdgcn_cvt_pk_fp8_f32(
                        pe_val2(cx, cy, kb + 2), pe_val2(cx, cy, kb + 3), p, true);
                    v[e] = p;
                }
                if (ks == 0) af0[mt] = v; else af1[mt] = v;
            }
        }
        __syncthreads();   // drains W staging
        MFMA_HALF(smem, 0, af0)
        MFMA_HALF(smem, 1, af1)
        __syncthreads();
    } else {
        // ---- prologue: stage W(it=0) into buf0; load A(ks=0,1) ----
#pragma unroll
        for (int p = 0; p < 4; p++) {
            int g = p * 256 + t;
            load_lds16((const void*)(wslab + g * 16), (void*)(smem + g * 16));
        }
        i32x8 afc0[2], afc1[2], afn0[2], afn1[2];
        LOAD_AF(afc0, 0)
        LOAD_AF(afc1, 1)
        __syncthreads();   // drains W staging + A loads

#pragma unroll 1
        for (int it = 0; it < nIt; it++) {
            u8* bufc = smem + ((it & 1) ? 16384 : 0);
            u8* bufn = smem + ((it & 1) ? 0 : 16384);
            // issue next-iter loads FIRST (consumed after this iter's barrier)
            if (it + 1 < nIt) {
                const u8* ws = wslab + (size_t)(it + 1) * 16384;
#pragma unroll
                for (int p = 0; p < 4; p++) {
                    int g = p * 256 + t;
                    load_lds16((const void*)(ws + g * 16), (void*)(bufn + g * 16));
                }
                LOAD_AF(afn0, 2 * (it + 1))
                LOAD_AF(afn1, 2 * (it + 1) + 1)
                asm volatile("" ::: "memory");   // pin prefetch issue early
            }
            // compute current iter (16 x 32x32x64 MFMA)
            MFMA_HALF(bufc, 0, afc0)
            MFMA_HALF(bufc, 1, afc1)
            __syncthreads();   // drain: next W staged, next A landed, buf free
#pragma unroll
            for (int mt = 0; mt < 2; mt++) { afc0[mt] = afn0[mt]; afc1[mt] = afn1[mt]; }
        }
    }
#undef LOAD_AF
#undef MFMA_HALF

    // lane element (mt, nt, reg): m = bm*256 + wm*64 + mt*32 + r32,
    //   n = bn*128 + nt*32 + (reg&3) + 8*(reg>>2) + 4*hl
    if constexpr (MODE == 0) {
        // Repack to next layer's A_t (K'=NH): eb = [seg(16)=m32l*2+ksl][2 KB]
        u8* eb = smem;
#pragma unroll
        for (int mt = 0; mt < 2; mt++) {
#pragma unroll
            for (int nt = 0; nt < 4; nt++) {
                int kh  = nt & 1;
                int seg = (wm * 2 + mt) * 2 + (nt >> 1);
#pragma unroll
                for (int g = 0; g < 4; g++) {
                    int nbase = nt * 32 + 8 * g + 4 * hl;
                    f32x4 b4 = *(const f32x4*)(bb + bn * 128 + nbase);
                    float v0 = fmaxf(acc[mt][nt][4 * g + 0] + b4[0], 0.0f);
                    float v1 = fmaxf(acc[mt][nt][4 * g + 1] + b4[1], 0.0f);
                    float v2 = fmaxf(acc[mt][nt][4 * g + 2] + b4[2], 0.0f);
                    float v3 = fmaxf(acc[mt][nt][4 * g + 3] + b4[3], 0.0f);
                    int p = __builtin_amdgcn_cvt_pk_fp8_f32(v0, v1, 0, false);
                    p     = __builtin_amdgcn_cvt_pk_fp8_f32(v2, v3, p, true);
                    int h   = g >> 1;
                    int idx = seg * 2048 + ((h * 2 + kh) * 32 + r32) * 16
                            + ((8 * g + 4 * hl) & 15);
                    *(int*)(eb + idx) = p;
                }
            }
        }
        __syncthreads();
#pragma unroll
        for (int rd = 0; rd < 8; rd++) {
            int g2  = rd * 256 + t;            // dwordx4 index 0..2047
            int seg = g2 >> 7, off = (g2 & 127) * 16;
            int m32l = seg >> 1, ksl = seg & 1;
            i32x4 v = *(const i32x4*)(eb + seg * 2048 + off);
            *(i32x4*)(O + ((size_t)((bm * 8 + m32l) * (NH >> 6) + bn * 2 + ksl)) * 2048
                      + off) = v;
        }
    } else {
#pragma unroll
        for (int mt = 0; mt < 2; mt++) {
            float p0 = 0.f, p1 = 0.f, p2 = 0.f;
#pragma unroll
            for (int nt = 0; nt < 4; nt++) {
#pragma unroll
                for (int g = 0; g < 4; g++) {
                    int nbase = bn * 128 + nt * 32 + 8 * g + 4 * hl;
                    f32x4 b4 = *(const f32x4*)(bb + nbase);
#pragma unroll
                    for (int rr = 0; rr < 4; rr++) {
                        float val = fmaxf(acc[mt][nt][4 * g + rr] + b4[rr], 0.0f);
                        const float* wo = Wout + (size_t)(nbase + rr) * NV;
                        p0 += val * wo[0]; p1 += val * wo[1]; p2 += val * wo[2];
                    }
                }
            }
            // lane l and l^32 hold the complementary n-halves of the same m
            p0 += __shfl_xor(p0, 32);
            p1 += __shfl_xor(p1, 32);
            p2 += __shfl_xor(p2, 32);
            if (hl == 0) {
                int m = bm * 256 + wm * 64 + mt * 32 + r32;
                atomicAdd(&out[(size_t)m * NV + 0], p0);
                atomicAdd(&out[(size_t)m * NV + 1], p1);
                atomicAdd(&out[(size_t)m * NV + 2], p2);
            }
        }
    }
}

// ---------------------------------------------------------------------------
extern "C" void kernel_launch(void* const* d_in, const int* in_sizes, int n_in,
                              void* d_out, int out_size, void* d_ws, size_t ws_size,
                              hipStream_t stream) {
    const float* coords     = (const float*)d_in[0];
    const int*   latent_idx = (const int*)d_in[1];
    const float* latents    = (const float*)d_in[2];
    const float* codebooks  = (const float*)d_in[3];
    const float* mod_W      = (const float*)d_in[4];
    const float* mod_b      = (const float*)d_in[5];
    const float* dec_W0     = (const float*)d_in[6];
    const float* dec_b0     = (const float*)d_in[7];
    const float* dec_Wh     = (const float*)d_in[8];
    const float* dec_bh     = (const float*)d_in[9];
    const float* dec_Wout   = (const float*)d_in[10];
    const float* dec_bout   = (const float*)d_in[11];
    float* out = (float*)d_out;

    // ---- workspace layout (fixed part ~4.35 MB) ----
    char* wsb = (char*)d_ws;
    float* zq  = (float*)(wsb + 0);                        //      256 B
    float* bb  = (float*)(wsb + 256);                      //   20,480 B
    u8*    W0T = (u8*)(wsb + 20736);                       //  131,072 B  tiled
    u8*    WhT = (u8*)(wsb + 151808);                      // 4,194,304 B tiled
    const size_t fixed_end = 4346368;                      // 256-aligned

    // adaptive chunk: cap 65536 (single chunk, ws ~139 MB), halve until fits;
    // floor 2048 so Mb = Bc/256 stays a multiple of 8 (capture-safe).
    int Bc = 65536;
    while (Bc > 2048 && fixed_end + 2 * (size_t)Bc * NH > ws_size)
        Bc >>= 1;
    int Mb = Bc / 256;   // m-tiles of 256

    u8* hA = (u8*)(wsb + fixed_end);                       // [Bc][1024] fp8 A_t
    u8* hB = hA + (size_t)Bc * NH;                         // [Bc][1024] fp8 A_t

    // ---- one-time (per call) small kernels ----
    vq_kernel<<<1, 1024, 0, stream>>>(latents, latent_idx, codebooks, zq, out);
    betas_init_kernel<<<(5120 + NB * NV) / 256, 256, 0, stream>>>(
        zq, mod_W, mod_b, dec_b0, dec_bh, bb, dec_bout, out);
    prep_kernel<<<dim3(32, 32, 5), dim3(32, 8), 0, stream>>>(
        dec_W0, dec_Wh, W0T, WhT);

    // ---- chunked 5-layer MLP, output layer fused into the last GEMM ----
    for (int c0 = 0; c0 < NB; c0 += Bc) {
        gemm_kernel<0, K0P><<<8 * Mb, 256, 0, stream>>>(
            nullptr, W0T, bb + 0 * NH, hA, nullptr, nullptr,
            coords + (size_t)c0 * NC, Mb);
        gemm_kernel<0, NH><<<8 * Mb, 256, 0, stream>>>(
            hA, WhT + 0 * (size_t)NH * NH, bb + 1 * NH, hB, nullptr, nullptr,
            nullptr, Mb);
        gemm_kernel<0, NH><<<8 * Mb, 256, 0, stream>>>(
            hB, WhT + 1 * (size_t)NH * NH, bb + 2 * NH, hA, nullptr, nullptr,
            nullptr, Mb);
        gemm_kernel<0, NH><<<8 * Mb, 256, 0, stream>>>(
            hA, WhT + 2 * (size_t)NH * NH, bb + 3 * NH, hB, nullptr, nullptr,
            nullptr, Mb);
        gemm_kernel<1, NH><<<8 * Mb, 256, 0, stream>>>(
            hB, WhT + 3 * (size_t)NH * NH, bb + 4 * NH, nullptr,
            dec_Wout, out + (size_t)c0 * NV, nullptr, Mb);
    }
}

// Round 11
// 467.564 us; speedup vs baseline: 1.1866x; 1.1866x over previous
//
#include <hip/hip_runtime.h>
#include <hip/hip_bf16.h>
#include <stdint.h>

// ---- problem constants ----
#define NB   65536      // batch points
#define NC   2
#define NV   3
#define ND   64
#define NK   1024       // codebook entries
#define NS   4
#define NH   1024
#define NL   5
#define NF   25
#define NIN  102
#define K0P  128        // padded layer-0 K

typedef float f32x4  __attribute__((ext_vector_type(4)));
typedef float f32x16 __attribute__((ext_vector_type(16)));
typedef int   i32x4  __attribute__((ext_vector_type(4)));
typedef int   i32x8  __attribute__((ext_vector_type(8)));
typedef unsigned char u8;

__device__ __forceinline__ void load_lds16(const void* g, void* l) {
    __builtin_amdgcn_global_load_lds(
        (const __attribute__((address_space(1))) void*)g,
        (__attribute__((address_space(3))) void*)l,
        16, 0, 0);
}

// fp8 e4m3 scalar convert (RNE, saturating): low byte of cvt_pk
__device__ __forceinline__ u8 to_fp8(float x) {
    return (u8)(__builtin_amdgcn_cvt_pk_fp8_f32(x, 0.0f, 0, false) & 0xff);
}

// 32x32x64 MX-fp8 MFMA. Swapped operands: src0 = W (n-dim on D "rows"),
// src1 = A (m-dim on D "cols"). D: col = lane&31 (m), row(n) =
// (reg&3) + 8*(reg>>2) + 4*(lane>>5), reg in [0,16).
__device__ __forceinline__ f32x16 mfma32(i32x8 wf, i32x8 af, f32x16 c) {
    return __builtin_amdgcn_mfma_scale_f32_32x32x64_f8f6f4(
        wf, af, c, 0, 0,
        0, 0x79797979,    // scale src0 (W): 2^-6
        0, 0x7f7f7f7f);   // scale src1 (A): 2^0
}

// ===========================================================================
// TILED OPERAND LAYOUTS (R21 — 32x32x64 fragments, half-split for stride-16)
// Fragment need (both operands): lane l holds X[row = 32-tile + (l&31)]
//   [k = ks*64 + (l>>5)*32 + 0..31], i.e. kh = l>>5, r32 = l&31, 32 k-bytes.
// Half-split storage of each (tile, ks) 2 KB chunk: [h(2)][kh(2)][r32(32)]
//   [b16(16)], h = upper/lower 16 of the 32 k-bytes. Then lane l reads
//   lo = chunk + l*16, hi = chunk + 1024 + l*16 (both stride-16: conflict-
//   free ds_read_b128 / fully-coalesced global dwordx4).
//  W_t: per bn (128 n): [ks(K/64)][j32(4)][h][kh][r32][b16]
//       -> per-(bn, 128-K iter) slab = 16 KB contiguous (2 ks) for staging.
//  A_t: [m32][ks(K/64)][h][kh][r32][b16] -> 2 KB chunk per (m32, ks).
// ===========================================================================

// ---------------------------------------------------------------------------
// VQ kernel: single block, 1024 threads (one codebook row per thread). fp32.
// R22: ssq sum wave-parallelized (was a 64-iter serial loop on t==0, x4).
// ---------------------------------------------------------------------------
__global__ __launch_bounds__(1024) void vq_kernel(
    const float* __restrict__ latents, const int* __restrict__ latent_idx,
    const float* __restrict__ codebooks, float* __restrict__ zq_out,
    float* __restrict__ out) {
    __shared__ float zcur[ND], resid[ND], zqsum[ND], ssq[ND];
    __shared__ float sDw[16];
    __shared__ int   sKw[16];
    __shared__ int   sBest;
    int t = threadIdx.x, lane = t & 63, wv = t >> 6;
    const float* img = latents + (size_t)latent_idx[0] * (NS * ND);
    if (t < ND) { resid[t] = 0.f; zqsum[t] = 0.f; }
    __syncthreads();
    float lossAcc = 0.f;   // thread 0 only
    for (int s = 0; s < NS; s++) {
        if (t < ND) {
            float iv = img[s * ND + t];
            float r  = resid[t] + iv;
            resid[t] = r;
            zcur[t]  = (s == 0) ? iv : (r - zqsum[t]);
        }
        __syncthreads();
        float zz = 0.f;
#pragma unroll
        for (int d = 0; d < ND; d++) { float z = zcur[d]; zz += z * z; }
        const float4* e4 = (const float4*)(codebooks + ((size_t)s * NK + t) * ND);
        float dot = 0.f, ee = 0.f;
#pragma unroll
        for (int i = 0; i < 16; i++) {
            float4 v = e4[i];
            dot += zcur[4 * i + 0] * v.x; dot += zcur[4 * i + 1] * v.y;
            dot += zcur[4 * i + 2] * v.z; dot += zcur[4 * i + 3] * v.w;
            ee  += v.x * v.x; ee += v.y * v.y; ee += v.z * v.z; ee += v.w * v.w;
        }
        float dmin = zz - 2.0f * dot + ee;
        int   kmin = t;
#pragma unroll
        for (int m = 1; m < 64; m <<= 1) {
            float d2 = __shfl_xor(dmin, m);
            int   k2 = __shfl_xor(kmin, m);
            if (d2 < dmin || (d2 == dmin && k2 < kmin)) { dmin = d2; kmin = k2; }
        }
        if (lane == 0) { sDw[wv] = dmin; sKw[wv] = kmin; }
        __syncthreads();
        if (t == 0) {
            float bd = sDw[0]; int bk = sKw[0];
            for (int w = 1; w < 16; w++) {
                float d2 = sDw[w]; int k2 = sKw[w];
                if (d2 < bd || (d2 == bd && k2 < bk)) { bd = d2; bk = k2; }
            }
            sBest = bk;
            out[NB * NV + s] = (float)bk;
        }
        __syncthreads();
        int best = sBest;
        const float* eb = codebooks + ((size_t)s * NK + best) * ND;
        if (t < ND) {
            float zq = eb[t];
            float d  = zq - zcur[t];
            ssq[t]   = d * d;
            zqsum[t] = zqsum[t] + (zq + (zcur[t] - zq));   // z_q_st forward (exact ref arith)
        }
        __syncthreads();
        if (t < 64) {   // wave 0: parallel 64-wide sum (was serial on t==0)
            float sum = ssq[t];
#pragma unroll
            for (int m = 1; m < 64; m <<= 1) sum += __shfl_xor(sum, m);
            if (t == 0) lossAcc += 0.25f * (sum / (float)ND);
        }
    }
    if (t < ND) zq_out[t] = zqsum[t];
    if (t == 0) out[NB * NV + NS] = lossAcc;
}

// ---------------------------------------------------------------------------
// betas (fused with decoder biases) + out-init, one launch (R22).
// g < 5120: betas; else: out[g-5120] = bout[(g-5120) % NV].
// ---------------------------------------------------------------------------
__global__ __launch_bounds__(256) void betas_init_kernel(
    const float* __restrict__ zq, const float* __restrict__ mod_W,
    const float* __restrict__ mod_b, const float* __restrict__ b0,
    const float* __restrict__ bh, float* __restrict__ bb,
    const float* __restrict__ bout, float* __restrict__ out) {
    int g = blockIdx.x * 256 + threadIdx.x;
    if (g < 5120) {
        int l = g >> 10, n = g & 1023;
        float acc = mod_b[g];
        for (int d = 0; d < ND; d++) acc += zq[d] * mod_W[(size_t)(l * ND + d) * NH + n];
        acc += (l == 0) ? b0[n] : bh[(size_t)(l - 1) * NH + n];
        bb[g] = acc;
    } else {
        int o = g - 5120;
        if (o < NB * NV) out[o] = bout[o % NV];
    }
}

// ---------------------------------------------------------------------------
// Weight prep (R22: both W0 and Wh in ONE launch, z-keyed):
// fp32 [Ks][1024] -> fp8 e4m3 W_t (32x32x64 half-split tiling, x64 scale
// undone by the MFMA e8m0 scale 2^-6). Zero-pad k>=Ks.
// z<4: Wh layer z (Ks=Kp=NH). z==4: W0 (Ks=NIN, Kp=K0P; only x<4 active).
// ---------------------------------------------------------------------------
__global__ __launch_bounds__(256) void prep_kernel(
    const float* __restrict__ dec_W0, const float* __restrict__ dec_Wh,
    u8* __restrict__ W0T, u8* __restrict__ WhT) {
    int z = blockIdx.z;
    const float* src; u8* dst; int Ks, Kp;
    if (z < 4) {
        src = dec_Wh + (size_t)z * NH * NH; dst = WhT + (size_t)z * NH * NH;
        Ks = NH; Kp = NH;
    } else {
        if (blockIdx.x >= 4) return;   // whole block returns: barrier-safe
        src = dec_W0; dst = W0T; Ks = NIN; Kp = K0P;
    }
    __shared__ float tile[32][33];
    int k0 = blockIdx.x * 32, n0 = blockIdx.y * 32;
    int tx = threadIdx.x, ty = threadIdx.y;   // (32, 8)
    for (int i = 0; i < 4; i++) {
        int k = k0 + ty + i * 8;
        int n = n0 + tx;
        tile[ty + i * 8][tx] = (k < Ks) ? src[(size_t)k * NH + n] : 0.0f;
    }
    __syncthreads();
    for (int i = 0; i < 4; i++) {
        int n = n0 + ty + i * 8;
        int k = k0 + tx;
        int bn = n >> 7, j32 = (n >> 5) & 3, r32 = n & 31;
        int ks = k >> 6, kh = (k >> 5) & 1, h = (k >> 4) & 1, b16 = k & 15;
        size_t flat = (size_t)bn * ((size_t)Kp * 128)
                    + ((size_t)(((ks * 4 + j32) * 2 + h) * 2 + kh) * 32 + r32) * 16 + b16;
        dst[flat] = to_fp8(tile[tx][ty + i * 8] * 64.0f);
    }
}

// ---------------------------------------------------------------------------
// Positional encoding -> fp8 A_t (32x32x64 half-split, K=128 -> ks in {0,1})
// R23: restored as a dedicated kernel (R21 form). R22 fused it into gemm0
// and paid 198 us of VALU: 128 libm sinf/cosf per lane x 8x bn-redundancy
// (VALUBusy 67%, MfmaUtil 1.7%). Dedicated kernel: 4 values/thread, once.
// ---------------------------------------------------------------------------
__device__ __forceinline__ float pe_val(const float* coords, int m, int k) {
    if (k < 2) return coords[m * 2 + k];
    if (k >= NIN) return 0.0f;
    int u = k - 2;
    int f = u >> 2, r = u & 3;
    float c = coords[m * 2 + (r & 1)];
    float a = c * __builtin_ldexpf(3.14159274101257324f, f);
    return (r < 2) ? sinf(a) : cosf(a);
}

__global__ __launch_bounds__(256) void pe_kernel(
    const float* __restrict__ coords, u8* __restrict__ pe) {
    int g = blockIdx.x * 256 + threadIdx.x;   // < Bc*32
    int m = g >> 5, k4 = (g & 31) * 4;
    float v0 = pe_val(coords, m, k4 + 0);
    float v1 = pe_val(coords, m, k4 + 1);
    float v2 = pe_val(coords, m, k4 + 2);
    float v3 = pe_val(coords, m, k4 + 3);
    int p = __builtin_amdgcn_cvt_pk_fp8_f32(v0, v1, 0, false);
    p     = __builtin_amdgcn_cvt_pk_fp8_f32(v2, v3, p, true);
    int m32 = m >> 5, r32 = m & 31;
    int ks = k4 >> 6, kh = (k4 >> 5) & 1, h = (k4 >> 4) & 1, b16 = k4 & 15;
    *(int*)(pe + (size_t)(m32 * 2 + ks) * 2048
            + ((h * 2 + kh) * 32 + r32) * 16 + b16) = p;
}

// ---------------------------------------------------------------------------
// MX-fp8 MFMA GEMM, R23: R21's verified 32x32x64 skeleton (86.4 us/NH layer,
// MfmaUtil 32.5%, zero spill/conflict). NH path keeps R22's neutral prefetch
// fence. K0P path back to reading the staged A_t from pe_kernel.
// Structure: 256m x 128n block, 4 waves of 64m x 128n (2 m-tiles x 4
// n-tiles of 32), 256 thr, launch_bounds(256,2), W via 2 x 16 KB LDS dbuf
// staged per 128-K iter, A direct global->reg, ONE __syncthreads per iter.
// MODE 0: relu(acc+bb) -> fp8, repack to next layer's A_t via LDS, coalesced.
// MODE 1: out[m][v] += relu(acc+bb).Wout[n][v], lane^32 shfl + atomicAdd.
// ---------------------------------------------------------------------------
template <int MODE, int KT>
__global__ __launch_bounds__(256, 2) void gemm_kernel(
    const u8* __restrict__ A, const u8* __restrict__ W,
    const float* __restrict__ bb, u8* __restrict__ O,
    const float* __restrict__ Wout, float* __restrict__ out, int Mb) {
    __shared__ __align__(16) u8 smem[32768];
    int t   = threadIdx.x;
    int fid = blockIdx.x;
    int xcd = fid & 7;
    int j8  = fid >> 3;                 // 0..Mb-1
    int bn  = j8 & 7;                   // fastest within an XCD
    int bm  = xcd * (Mb >> 3) + (j8 >> 3);
    int lane = t & 63, wm = t >> 6;     // wave owns m-slice wm*64..+63
    int r32  = lane & 31, hl = lane >> 5;
    constexpr int nIt = KT >> 7;        // 128-K iters
    constexpr int nKs = KT >> 6;        // 64-K steps

    const u8* wslab = W + (size_t)bn * ((size_t)KT * 128);
    const u8* abase = A + ((size_t)(bm * 8 + wm * 2) * nKs) * 2048 + lane * 16;

    f32x16 acc[2][4];
#pragma unroll
    for (int i = 0; i < 2; i++)
#pragma unroll
        for (int j = 0; j < 4; j++)
#pragma unroll
            for (int e = 0; e < 16; e++) acc[i][j][e] = 0.0f;

    // A frags for k-step KS (global): dst[mt], 8 VGPR each
#define LOAD_AF(dst, KS)                                                       \
    {                                                                          \
        _Pragma("unroll")                                                      \
        for (int mt = 0; mt < 2; mt++) {                                       \
            const u8* p = abase + ((size_t)mt * nKs + (KS)) * 2048;            \
            i32x4 lo = *(const i32x4*)(p);                                     \
            i32x4 hi = *(const i32x4*)(p + 1024);                              \
            dst[mt] = __builtin_shufflevector(lo, hi, 0, 1, 2, 3, 4, 5, 6, 7); \
        }                                                                      \
    }
    // one 64-K half of an iter: 4 W-frag reads + 8 MFMA
#define MFMA_HALF(base, KSL, AF)                                               \
    {                                                                          \
        _Pragma("unroll")                                                      \
        for (int j = 0; j < 4; j++) {                                          \
            const u8* c = (base) + (KSL) * 8192 + j * 2048 + lane * 16;        \
            i32x4 lo = *(const i32x4*)(c);                                     \
            i32x4 hi = *(const i32x4*)(c + 1024);                              \
            i32x8 wf = __builtin_shufflevector(lo, hi, 0, 1, 2, 3, 4, 5, 6, 7);\
            acc[0][j] = mfma32(wf, AF[0], acc[0][j]);                          \
            acc[1][j] = mfma32(wf, AF[1], acc[1][j]);                          \
        }                                                                      \
    }

    if constexpr (nIt == 1) {
        // ---- K0P path: single 16 KB slab, both 64-K halves ----
#pragma unroll
        for (int p = 0; p < 4; p++) {
            int g = p * 256 + t;
            load_lds16((const void*)(wslab + g * 16), (void*)(smem + g * 16));
        }
        i32x8 af0[2], af1[2];
        LOAD_AF(af0, 0)
        LOAD_AF(af1, 1)
        __syncthreads();   // drains W staging + A loads
        MFMA_HALF(smem, 0, af0)
        MFMA_HALF(smem, 1, af1)
        __syncthreads();
    } else {
        // ---- prologue: stage W(it=0) into buf0; load A(ks=0,1) ----
#pragma unroll
        for (int p = 0; p < 4; p++) {
            int g = p * 256 + t;
            load_lds16((const void*)(wslab + g * 16), (void*)(smem + g * 16));
        }
        i32x8 afc0[2], afc1[2], afn0[2], afn1[2];
        LOAD_AF(afc0, 0)
        LOAD_AF(afc1, 1)
        __syncthreads();   // drains W staging + A loads

#pragma unroll 1
        for (int it = 0; it < nIt; it++) {
            u8* bufc = smem + ((it & 1) ? 16384 : 0);
            u8* bufn = smem + ((it & 1) ? 0 : 16384);
            // issue next-iter loads FIRST (consumed after this iter's barrier)
            if (it + 1 < nIt) {
                const u8* ws = wslab + (size_t)(it + 1) * 16384;
#pragma unroll
                for (int p = 0; p < 4; p++) {
                    int g = p * 256 + t;
                    load_lds16((const void*)(ws + g * 16), (void*)(bufn + g * 16));
                }
                LOAD_AF(afn0, 2 * (it + 1))
                LOAD_AF(afn1, 2 * (it + 1) + 1)
                asm volatile("" ::: "memory");   // pin prefetch issue early
            }
            // compute current iter (16 x 32x32x64 MFMA)
            MFMA_HALF(bufc, 0, afc0)
            MFMA_HALF(bufc, 1, afc1)
            __syncthreads();   // drain: next W staged, next A landed, buf free
#pragma unroll
            for (int mt = 0; mt < 2; mt++) { afc0[mt] = afn0[mt]; afc1[mt] = afn1[mt]; }
        }
    }
#undef LOAD_AF
#undef MFMA_HALF

    // lane element (mt, nt, reg): m = bm*256 + wm*64 + mt*32 + r32,
    //   n = bn*128 + nt*32 + (reg&3) + 8*(reg>>2) + 4*hl
    if constexpr (MODE == 0) {
        // Repack to next layer's A_t (K'=NH): eb = [seg(16)=m32l*2+ksl][2 KB]
        u8* eb = smem;
#pragma unroll
        for (int mt = 0; mt < 2; mt++) {
#pragma unroll
            for (int nt = 0; nt < 4; nt++) {
                int kh  = nt & 1;
                int seg = (wm * 2 + mt) * 2 + (nt >> 1);
#pragma unroll
                for (int g = 0; g < 4; g++) {
                    int nbase = nt * 32 + 8 * g + 4 * hl;
                    f32x4 b4 = *(const f32x4*)(bb + bn * 128 + nbase);
                    float v0 = fmaxf(acc[mt][nt][4 * g + 0] + b4[0], 0.0f);
                    float v1 = fmaxf(acc[mt][nt][4 * g + 1] + b4[1], 0.0f);
                    float v2 = fmaxf(acc[mt][nt][4 * g + 2] + b4[2], 0.0f);
                    float v3 = fmaxf(acc[mt][nt][4 * g + 3] + b4[3], 0.0f);
                    int p = __builtin_amdgcn_cvt_pk_fp8_f32(v0, v1, 0, false);
                    p     = __builtin_amdgcn_cvt_pk_fp8_f32(v2, v3, p, true);
                    int h   = g >> 1;
                    int idx = seg * 2048 + ((h * 2 + kh) * 32 + r32) * 16
                            + ((8 * g + 4 * hl) & 15);
                    *(int*)(eb + idx) = p;
                }
            }
        }
        __syncthreads();
#pragma unroll
        for (int rd = 0; rd < 8; rd++) {
            int g2  = rd * 256 + t;            // dwordx4 index 0..2047
            int seg = g2 >> 7, off = (g2 & 127) * 16;
            int m32l = seg >> 1, ksl = seg & 1;
            i32x4 v = *(const i32x4*)(eb + seg * 2048 + off);
            *(i32x4*)(O + ((size_t)((bm * 8 + m32l) * (NH >> 6) + bn * 2 + ksl)) * 2048
                      + off) = v;
        }
    } else {
#pragma unroll
        for (int mt = 0; mt < 2; mt++) {
            float p0 = 0.f, p1 = 0.f, p2 = 0.f;
#pragma unroll
            for (int nt = 0; nt < 4; nt++) {
#pragma unroll
                for (int g = 0; g < 4; g++) {
                    int nbase = bn * 128 + nt * 32 + 8 * g + 4 * hl;
                    f32x4 b4 = *(const f32x4*)(bb + nbase);
#pragma unroll
                    for (int rr = 0; rr < 4; rr++) {
                        float val = fmaxf(acc[mt][nt][4 * g + rr] + b4[rr], 0.0f);
                        const float* wo = Wout + (size_t)(nbase + rr) * NV;
                        p0 += val * wo[0]; p1 += val * wo[1]; p2 += val * wo[2];
                    }
                }
            }
            // lane l and l^32 hold the complementary n-halves of the same m
            p0 += __shfl_xor(p0, 32);
            p1 += __shfl_xor(p1, 32);
            p2 += __shfl_xor(p2, 32);
            if (hl == 0) {
                int m = bm * 256 + wm * 64 + mt * 32 + r32;
                atomicAdd(&out[(size_t)m * NV + 0], p0);
                atomicAdd(&out[(size_t)m * NV + 1], p1);
                atomicAdd(&out[(size_t)m * NV + 2], p2);
            }
        }
    }
}

// ---------------------------------------------------------------------------
extern "C" void kernel_launch(void* const* d_in, const int* in_sizes, int n_in,
                              void* d_out, int out_size, void* d_ws, size_t ws_size,
                              hipStream_t stream) {
    const float* coords     = (const float*)d_in[0];
    const int*   latent_idx = (const int*)d_in[1];
    const float* latents    = (const float*)d_in[2];
    const float* codebooks  = (const float*)d_in[3];
    const float* mod_W      = (const float*)d_in[4];
    const float* mod_b      = (const float*)d_in[5];
    const float* dec_W0     = (const float*)d_in[6];
    const float* dec_b0     = (const float*)d_in[7];
    const float* dec_Wh     = (const float*)d_in[8];
    const float* dec_bh     = (const float*)d_in[9];
    const float* dec_Wout   = (const float*)d_in[10];
    const float* dec_bout   = (const float*)d_in[11];
    float* out = (float*)d_out;

    // ---- workspace layout (fixed part ~4.35 MB) ----
    char* wsb = (char*)d_ws;
    float* zq  = (float*)(wsb + 0);                        //      256 B
    float* bb  = (float*)(wsb + 256);                      //   20,480 B
    u8*    W0T = (u8*)(wsb + 20736);                       //  131,072 B  tiled
    u8*    WhT = (u8*)(wsb + 151808);                      // 4,194,304 B tiled
    const size_t fixed_end = 4346368;                      // 256-aligned

    // adaptive chunk: cap 65536 (single chunk, ws ~139 MB), halve until fits;
    // floor 2048 so Mb = Bc/256 stays a multiple of 8 (capture-safe).
    int Bc = 65536;
    while (Bc > 2048 && fixed_end + 2 * (size_t)Bc * NH > ws_size)
        Bc >>= 1;
    int Mb = Bc / 256;   // m-tiles of 256

    u8* hA = (u8*)(wsb + fixed_end);                       // [Bc][1024] fp8 A_t
    u8* hB = hA + (size_t)Bc * NH;                         // [Bc][1024] fp8 A_t
    u8* pe = hB;   // pe A_t [Bc][128] aliases hB (dead before layer-1 writes hB)

    // ---- one-time (per call) small kernels ----
    vq_kernel<<<1, 1024, 0, stream>>>(latents, latent_idx, codebooks, zq, out);
    betas_init_kernel<<<(5120 + NB * NV) / 256, 256, 0, stream>>>(
        zq, mod_W, mod_b, dec_b0, dec_bh, bb, dec_bout, out);
    prep_kernel<<<dim3(32, 32, 5), dim3(32, 8), 0, stream>>>(
        dec_W0, dec_Wh, W0T, WhT);

    // ---- chunked 5-layer MLP, output layer fused into the last GEMM ----
    for (int c0 = 0; c0 < NB; c0 += Bc) {
        pe_kernel<<<(Bc * 32) / 256, 256, 0, stream>>>(coords + (size_t)c0 * NC, pe);
        gemm_kernel<0, K0P><<<8 * Mb, 256, 0, stream>>>(
            pe, W0T, bb + 0 * NH, hA, nullptr, nullptr, Mb);
        gemm_kernel<0, NH><<<8 * Mb, 256, 0, stream>>>(
            hA, WhT + 0 * (size_t)NH * NH, bb + 1 * NH, hB, nullptr, nullptr, Mb);
        gemm_kernel<0, NH><<<8 * Mb, 256, 0, stream>>>(
            hB, WhT + 1 * (size_t)NH * NH, bb + 2 * NH, hA, nullptr, nullptr, Mb);
        gemm_kernel<0, NH><<<8 * Mb, 256, 0, stream>>>(
            hA, WhT + 2 * (size_t)NH * NH, bb + 3 * NH, hB, nullptr, nullptr, Mb);
        gemm_kernel<1, NH><<<8 * Mb, 256, 0, stream>>>(
            hB, WhT + 3 * (size_t)NH * NH, bb + 4 * NH, nullptr,
            dec_Wout, out + (size_t)c0 * NV, Mb);
    }
}